// Round 6
// baseline (224.838 us; speedup 1.0000x reference)
//
#include <hip/hip_runtime.h>

// Fold (col2im 3D): x (1,16,8,8,8,4096) f32 -> out (1,16,68,68,68) f32
// CALIBRATION ROUND: identical kernel to round 4, launched TWICE per
// kernel_launch (pure overwrite-gather => idempotent, graph-safe).
// dur_us(this) - dur_us(round4) ~= one kernel's serialized duration,
// disambiguating kernel-time vs harness-fixed-overhead in dur_us.
//
// Bijection per dim: o = 4*m + kl, m in [0,17), kl in [0,4);
//   out[c,o1,o2,o3] = sum over kh in {0,1}^3 of
//     x[c, 4*kh1+kl1, 4*kh2+kl2, 4*kh3+kl3, m1-kh1, m2-kh2, m3-kh3] (clipped)
// Thread = (c, o1, o2, kl3, b); per (kh1,kh2): two aligned float4 loads,
// cross-quad elements via __shfl within 16-lane groups (group-uniform masks).

#define TOTAL_THREADS (16 * 68 * 68 * 16)  // 1,183,744 -> 4624 blocks of 256

__global__ __launch_bounds__(256) void fold_kernel(const float* __restrict__ x,
                                                   float* __restrict__ out) {
    int t = blockIdx.x * 256 + threadIdx.x;
    int b   = t & 3;
    int kl3 = (t >> 2) & 3;
    int r   = t >> 4;
    int o2 = r % 68;
    r /= 68;
    int o1 = r % 68;
    int c  = r / 68;

    int m1 = o1 >> 2, kl1 = o1 & 3;
    int m2 = o2 >> 2, kl2 = o2 & 3;

    float a0 = 0.f, a1 = 0.f, a2 = 0.f, a3 = 0.f, a4 = 0.f;

    // input strides: c 2^21, k1 2^18, k2 2^15, k3 2^12, n1 2^8, n2 2^4, n3 1
#pragma unroll
    for (int kh1 = 0; kh1 < 2; ++kh1) {
        int n1 = m1 - kh1;
        bool v1 = (unsigned)n1 < 16u;
        int k1 = kl1 + 4 * kh1;
#pragma unroll
        for (int kh2 = 0; kh2 < 2; ++kh2) {
            int n2 = m2 - kh2;
            bool ok = v1 && ((unsigned)n2 < 16u);  // uniform per 16-lane group
            int k2 = kl2 + 4 * kh2;

            ptrdiff_t base = ((ptrdiff_t)c << 21) + ((ptrdiff_t)k1 << 18)
                           + ((ptrdiff_t)k2 << 15) + ((ptrdiff_t)n1 << 8)
                           + ((ptrdiff_t)n2 << 4) + 4 * b;

            float4 A = make_float4(0.f, 0.f, 0.f, 0.f);
            float4 B = make_float4(0.f, 0.f, 0.f, 0.f);
            if (ok) {
                A = *reinterpret_cast<const float4*>(x + base + ((ptrdiff_t)kl3 << 12));
                B = *reinterpret_cast<const float4*>(x + base + ((ptrdiff_t)(kl3 + 4) << 12));
            }
            float s_up = __shfl_up(B.w, 1);    // lane b-1's B.w  (n3 = 4b-1)
            float s_dn = __shfl_down(B.w, 3);  // lane b+3's B.w  (n3 = 15, b==0)
            if (ok) {
                a0 += A.x;
                a1 += A.y + B.x;
                a2 += A.z + B.y;
                a3 += A.w + B.z;
                if (b > 0) a0 += s_up;
                if (b == 0) a4 += s_dn;
            }
        }
    }

    size_t ob = ((((size_t)c * 68) + o1) * 68 + o2) * 68 + (size_t)(16 * b + kl3);
    out[ob]      = a0;
    out[ob + 4]  = a1;
    out[ob + 8]  = a2;
    out[ob + 12] = a3;
    if (b == 0) out[ob + 64] = a4;  // m3 = 16 tail
}

extern "C" void kernel_launch(void* const* d_in, const int* in_sizes, int n_in,
                              void* d_out, int out_size, void* d_ws, size_t ws_size,
                              hipStream_t stream) {
    const float* x = (const float*)d_in[0];
    float* out = (float*)d_out;
    dim3 grid(TOTAL_THREADS / 256), block(256);
    // Launched twice on purpose (calibration): second launch overwrites with
    // identical values; delta vs single-launch round isolates kernel time.
    hipLaunchKernelGGL(fold_kernel, grid, block, 0, stream, x, out);
    hipLaunchKernelGGL(fold_kernel, grid, block, 0, stream, x, out);
}

// Round 7
// 194.968 us; speedup vs baseline: 1.1532x; 1.1532x over previous
//
#include <hip/hip_runtime.h>

// Fold (col2im 3D): x (1,16,8,8,8,4096) f32 -> out (1,16,68,68,68) f32
// KS=8, ST=4, n=16, H=W=D=68.
// Bijection per dim: o = 4*m + kl, m in [0,17), kl in [0,4);
//   out[c,o1,o2,o3] = sum over kh in {0,1}^3 of
//     x[c, 4*kh1+kl1, 4*kh2+kl2, 4*kh3+kl3, m1-kh1, m2-kh2, m3-kh3] (bounds-clipped)
//
// Vectorized-gather mapping: thread = (c, o1, o2, kl3, b), b = n3-quad index.
// Thread owns outputs o3 = 16*b + kl3 + 4*i, i=0..3 (m3 = 4b+i), and b==0
// additionally owns m3=16 (o3 = 64+kl3).
// Per (kh1,kh2) combo: two aligned float4 loads cover all 8 contributions;
// cross-quad elements via __shfl within 16-lane groups (group-uniform masks).
// Every input element read exactly once; every output written exactly once.
//
// Calibration (round 6, double-launch): one kernel ~= 30.8 us vs 24.5 us
// HBM roofline (154 MB @ 6.3 TB/s) -> ~80% of achievable BW. dur_us is
// dominated by ~163 us of fixed harness poison/restore work.

#define TOTAL_THREADS (16 * 68 * 68 * 16)  // 1,183,744 -> 4624 blocks of 256

__global__ __launch_bounds__(256) void fold_kernel(const float* __restrict__ x,
                                                   float* __restrict__ out) {
    int t = blockIdx.x * 256 + threadIdx.x;
    int b   = t & 3;
    int kl3 = (t >> 2) & 3;
    int r   = t >> 4;
    int o2 = r % 68;
    r /= 68;
    int o1 = r % 68;
    int c  = r / 68;

    int m1 = o1 >> 2, kl1 = o1 & 3;
    int m2 = o2 >> 2, kl2 = o2 & 3;

    float a0 = 0.f, a1 = 0.f, a2 = 0.f, a3 = 0.f, a4 = 0.f;

    // input strides: c 2^21, k1 2^18, k2 2^15, k3 2^12, n1 2^8, n2 2^4, n3 1
#pragma unroll
    for (int kh1 = 0; kh1 < 2; ++kh1) {
        int n1 = m1 - kh1;
        bool v1 = (unsigned)n1 < 16u;
        int k1 = kl1 + 4 * kh1;
#pragma unroll
        for (int kh2 = 0; kh2 < 2; ++kh2) {
            int n2 = m2 - kh2;
            bool ok = v1 && ((unsigned)n2 < 16u);  // uniform per 16-lane group
            int k2 = kl2 + 4 * kh2;

            ptrdiff_t base = ((ptrdiff_t)c << 21) + ((ptrdiff_t)k1 << 18)
                           + ((ptrdiff_t)k2 << 15) + ((ptrdiff_t)n1 << 8)
                           + ((ptrdiff_t)n2 << 4) + 4 * b;

            float4 A = make_float4(0.f, 0.f, 0.f, 0.f);
            float4 B = make_float4(0.f, 0.f, 0.f, 0.f);
            if (ok) {
                A = *reinterpret_cast<const float4*>(x + base + ((ptrdiff_t)kl3 << 12));
                B = *reinterpret_cast<const float4*>(x + base + ((ptrdiff_t)(kl3 + 4) << 12));
            }
            float s_up = __shfl_up(B.w, 1);    // lane b-1's B.w  (n3 = 4b-1)
            float s_dn = __shfl_down(B.w, 3);  // lane b+3's B.w  (n3 = 15, b==0)
            if (ok) {
                a0 += A.x;
                a1 += A.y + B.x;
                a2 += A.z + B.y;
                a3 += A.w + B.z;
                if (b > 0) a0 += s_up;
                if (b == 0) a4 += s_dn;
            }
        }
    }

    // out strides: c 68^3, o1 68^2, o2 68, o3 1; this thread's o3 base = 16b+kl3
    size_t ob = ((((size_t)c * 68) + o1) * 68 + o2) * 68 + (size_t)(16 * b + kl3);
    out[ob]      = a0;
    out[ob + 4]  = a1;
    out[ob + 8]  = a2;
    out[ob + 12] = a3;
    if (b == 0) out[ob + 64] = a4;  // m3 = 16 tail
}

extern "C" void kernel_launch(void* const* d_in, const int* in_sizes, int n_in,
                              void* d_out, int out_size, void* d_ws, size_t ws_size,
                              hipStream_t stream) {
    const float* x = (const float*)d_in[0];
    float* out = (float*)d_out;
    dim3 grid(TOTAL_THREADS / 256), block(256);
    hipLaunchKernelGGL(fold_kernel, grid, block, 0, stream, x, out);
}